// Round 4
// baseline (1212.638 us; speedup 1.0000x reference)
//
#include <hip/hip_runtime.h>
#include <math.h>

// ---------------------------------------------------------------------------
// MPConv round 4: counting-sort by destination + lean VALU edge kernel.
//   prep:    Wab[128][64], W1cT[64][32], Wt2t[64][64] (bf16 transposed)
//   xab:     [N][128] bf16 = x @ [W1a|W1b]                     (MFMA)
//   sort:    hist -> scan -> permute (inv[e]=pos, src/dst_sorted)
//   eaw:     [E][64] bf16 = ea @ W1c + b1, written SORTED       (MFMA)
//   edge:    acc = xa[i]+xb[j]+eaw[p]; LN+GELU; merged atomics -> Hsum
//   final:   out = Hsum @ W2 + counts * b2                      (MFMA)
// ---------------------------------------------------------------------------

using short8 = __attribute__((ext_vector_type(8))) short;
using f32x4  = __attribute__((ext_vector_type(4))) float;

static __device__ __forceinline__ short f2bf(float f) {
    unsigned u = __float_as_uint(f);
    u += 0x7FFFu + ((u >> 16) & 1u);
    return (short)(u >> 16);
}
static __device__ __forceinline__ float bf2f(unsigned short u) {
    return __uint_as_float(((unsigned)u) << 16);
}
static __device__ __forceinline__ short8 pack8(float4 a, float4 b) {
    short8 r;
    r[0] = f2bf(a.x); r[1] = f2bf(a.y); r[2] = f2bf(a.z); r[3] = f2bf(a.w);
    r[4] = f2bf(b.x); r[5] = f2bf(b.y); r[6] = f2bf(b.z); r[7] = f2bf(b.w);
    return r;
}

// ---- weight prep ----------------------------------------------------------
__global__ void prep_weights3(const float* __restrict__ W1,
                              const float* __restrict__ W2,
                              short* __restrict__ Wab,    // [128][64]
                              short* __restrict__ W1cT,   // [64][32]
                              short* __restrict__ Wt2t)   // [64][64]
{
    int t = blockIdx.x * blockDim.x + threadIdx.x;
    if (t < 128 * 64) {
        int n = t / 64, k = t % 64;
        float v = (n < 64) ? W1[(size_t)k * 64 + n]
                           : W1[(size_t)(64 + k) * 64 + (n - 64)];
        Wab[t] = f2bf(v);
    } else if (t < 128 * 64 + 64 * 32) {
        int t2 = t - 128 * 64;
        int n = t2 / 32, k = t2 % 32;
        W1cT[t2] = f2bf(W1[(size_t)(128 + k) * 64 + n]);
    } else if (t < 128 * 64 + 64 * 32 + 64 * 64) {
        int t3 = t - 128 * 64 - 64 * 32;
        int n = t3 / 64, k = t3 % 64;
        Wt2t[t3] = f2bf(W2[(size_t)k * 64 + n]);
    }
}

// ---- xab = x @ [W1a|W1b], bf16 [N][128] ----------------------------------
__global__ __launch_bounds__(256) void precompute_xab(
    const float* __restrict__ x, const short* __restrict__ Wab,
    short* __restrict__ xab, int N)
{
    const int wave = threadIdx.x >> 6, lane = threadIdx.x & 63;
    const int g = lane >> 4, col = lane & 15;
    const int base = blockIdx.x * 256 + wave * 64;

    short8 af[4][2];
#pragma unroll
    for (int mt = 0; mt < 4; mt++) {
        int row = base + mt * 16 + col;
        row = (row < N) ? row : (N - 1);
#pragma unroll
        for (int ks = 0; ks < 2; ks++) {
            const float* s = x + (size_t)row * 64 + ks * 32 + g * 8;
            af[mt][ks] = pack8(*(const float4*)s, *(const float4*)(s + 4));
        }
    }
#pragma unroll
    for (int half = 0; half < 2; half++) {
        f32x4 acc[4][4];
#pragma unroll
        for (int mt = 0; mt < 4; mt++)
#pragma unroll
            for (int nt = 0; nt < 4; nt++)
                acc[mt][nt] = (f32x4){0.f, 0.f, 0.f, 0.f};
#pragma unroll
        for (int ks = 0; ks < 2; ks++) {
            short8 bf[4];
#pragma unroll
            for (int nt = 0; nt < 4; nt++)
                bf[nt] = *(const short8*)(Wab +
                    (size_t)(half * 64 + col + 16 * nt) * 64 + ks * 32 + g * 8);
#pragma unroll
            for (int mt = 0; mt < 4; mt++)
#pragma unroll
                for (int nt = 0; nt < 4; nt++)
                    acc[mt][nt] = __builtin_amdgcn_mfma_f32_16x16x32_bf16(
                        af[mt][ks], bf[nt], acc[mt][nt], 0, 0, 0);
        }
#pragma unroll
        for (int mt = 0; mt < 4; mt++)
#pragma unroll
            for (int r = 0; r < 4; r++) {
                int node = base + mt * 16 + g * 4 + r;
                if (node < N)
#pragma unroll
                    for (int nt = 0; nt < 4; nt++)
                        xab[(size_t)node * 128 + half * 64 + col + 16 * nt] =
                            f2bf(acc[mt][nt][r]);
            }
    }
}

// ---- sort pipeline --------------------------------------------------------
__global__ void hist_kernel(const int* __restrict__ ei, int* __restrict__ counts,
                            int E) {
    int e = blockIdx.x * blockDim.x + threadIdx.x;
    if (e < E) atomicAdd(&counts[ei[E + e]], 1);
}

__global__ void scan1(const int* __restrict__ counts, int* __restrict__ offs,
                      int* __restrict__ bsum, int N) {
    __shared__ int s[256];
    int i = blockIdx.x * 256 + threadIdx.x;
    int v = (i < N) ? counts[i] : 0;
    s[threadIdx.x] = v;
    __syncthreads();
#pragma unroll
    for (int off = 1; off < 256; off <<= 1) {
        int t = (threadIdx.x >= off) ? s[threadIdx.x - off] : 0;
        __syncthreads();
        s[threadIdx.x] += t;
        __syncthreads();
    }
    if (i < N) offs[i] = s[threadIdx.x] - v;          // exclusive within block
    if (threadIdx.x == 255) bsum[blockIdx.x] = s[255];
}

__global__ void scan2(int* __restrict__ bsum, int nB) {
    __shared__ int s[512];
    int v = (threadIdx.x < nB) ? bsum[threadIdx.x] : 0;
    s[threadIdx.x] = v;
    __syncthreads();
#pragma unroll
    for (int off = 1; off < 512; off <<= 1) {
        int t = (threadIdx.x >= off) ? s[threadIdx.x - off] : 0;
        __syncthreads();
        s[threadIdx.x] += t;
        __syncthreads();
    }
    if (threadIdx.x < nB) bsum[threadIdx.x] = s[threadIdx.x] - v;  // exclusive
}

__global__ void scan3(int* __restrict__ offs, const int* __restrict__ bsum,
                      int N) {
    int i = blockIdx.x * 256 + threadIdx.x;
    if (i < N) offs[i] += bsum[blockIdx.x];
}

__global__ void permute_kernel(const int* __restrict__ ei,
                               const int* __restrict__ offs,
                               int* __restrict__ cursor,
                               int* __restrict__ inv,
                               int* __restrict__ src_s,
                               int* __restrict__ dst_s, int E) {
    int e = blockIdx.x * blockDim.x + threadIdx.x;
    if (e < E) {
        int dst = ei[E + e];
        int pos = offs[dst] + atomicAdd(&cursor[dst], 1);
        inv[e] = pos;
        src_s[pos] = ei[e];
        dst_s[pos] = dst;
    }
}

// ---- eaw[pos] = ea[e] @ W1c + b1  (bf16, sorted order) -------------------
__global__ __launch_bounds__(256) void eaw_mfma(
    const float* __restrict__ ea, const short* __restrict__ W1cT,
    const float* __restrict__ b1, const int* __restrict__ inv,
    short* __restrict__ eaw, int E)
{
    const int wave = threadIdx.x >> 6, lane = threadIdx.x & 63;
    const int g = lane >> 4, col = lane & 15;
    const int eb = blockIdx.x * 256 + wave * 64;

    float b1c[4];
#pragma unroll
    for (int nt = 0; nt < 4; nt++) b1c[nt] = b1[col + 16 * nt];

    short8 af[4];
#pragma unroll
    for (int mt = 0; mt < 4; mt++) {
        int e = eb + mt * 16 + col;
        e = (e < E) ? e : (E - 1);
        const float* s = ea + (size_t)e * 32 + g * 8;
        af[mt] = pack8(*(const float4*)s, *(const float4*)(s + 4));
    }
    short8 bf[4];
#pragma unroll
    for (int nt = 0; nt < 4; nt++)
        bf[nt] = *(const short8*)(W1cT + (size_t)(col + 16 * nt) * 32 + g * 8);

    f32x4 acc[4][4];
#pragma unroll
    for (int mt = 0; mt < 4; mt++)
#pragma unroll
        for (int nt = 0; nt < 4; nt++)
            acc[mt][nt] = __builtin_amdgcn_mfma_f32_16x16x32_bf16(
                af[mt], bf[nt], (f32x4){0.f, 0.f, 0.f, 0.f}, 0, 0, 0);

#pragma unroll
    for (int mt = 0; mt < 4; mt++)
#pragma unroll
        for (int r = 0; r < 4; r++) {
            int e = eb + mt * 16 + g * 4 + r;
            if (e < E) {
                int pos = inv[e];
#pragma unroll
                for (int nt = 0; nt < 4; nt++)
                    eaw[(size_t)pos * 64 + col + 16 * nt] =
                        f2bf(acc[mt][nt][r] + b1c[nt]);
            }
        }
}

// ---- lean edge kernel: 16 lanes per sorted edge --------------------------
__global__ __launch_bounds__(256) void edge_ln(
    const unsigned short* __restrict__ xab,   // [N][128] bf16
    const unsigned short* __restrict__ eaw,   // [E][64] bf16 (sorted, +b1)
    const int* __restrict__ src_s, const int* __restrict__ dst_s,
    const float* __restrict__ gam, const float* __restrict__ bet,
    float* __restrict__ Hsum, int E)
{
    const int lane = threadIdx.x & 63;
    const int l = threadIdx.x & 15;
    const int p = (blockIdx.x * 256 + threadIdx.x) >> 4;   // sorted edge id
    if (p >= E) return;

    const int i = src_s[p];
    const int j = dst_s[p];

    ushort4 ua = *(const ushort4*)(xab + (size_t)i * 128 + 4 * l);
    ushort4 ub = *(const ushort4*)(xab + (size_t)j * 128 + 64 + 4 * l);
    ushort4 uw = *(const ushort4*)(eaw + (size_t)p * 64 + 4 * l);

    float4 acc;
    acc.x = bf2f(ua.x) + bf2f(ub.x) + bf2f(uw.x);
    acc.y = bf2f(ua.y) + bf2f(ub.y) + bf2f(uw.y);
    acc.z = bf2f(ua.z) + bf2f(ub.z) + bf2f(uw.z);
    acc.w = bf2f(ua.w) + bf2f(ub.w) + bf2f(uw.w);

    float s = acc.x + acc.y + acc.z + acc.w;
    float q = acc.x * acc.x + acc.y * acc.y + acc.z * acc.z + acc.w * acc.w;
#pragma unroll
    for (int m = 1; m < 16; m <<= 1) {
        s += __shfl_xor(s, m);
        q += __shfl_xor(q, m);
    }
    float mu  = s * (1.0f / 64.0f);
    float var = q * (1.0f / 64.0f) - mu * mu;
    float inv = rsqrtf(var + 1e-5f);

    float4 g4 = *(const float4*)(gam + 4 * l);
    float4 b4 = *(const float4*)(bet + 4 * l);
    float4 h;
    h.x = (acc.x - mu) * inv * g4.x + b4.x;
    h.y = (acc.y - mu) * inv * g4.y + b4.y;
    h.z = (acc.z - mu) * inv * g4.z + b4.z;
    h.w = (acc.w - mu) * inv * g4.w + b4.w;
    h.x = 0.5f * h.x * (1.0f + erff(h.x * 0.70710678118654752f));
    h.y = 0.5f * h.y * (1.0f + erff(h.y * 0.70710678118654752f));
    h.z = 0.5f * h.z * (1.0f + erff(h.z * 0.70710678118654752f));
    h.w = 0.5f * h.w * (1.0f + erff(h.w * 0.70710678118654752f));

    // merge the wave's 4 edges when they all share a destination (common
    // after the sort: avg degree 16) -> 4x fewer atomic ops
    int d0 = __shfl(j, lane & 15);                 // group 0's dst
    unsigned long long eq = __ballot(j == d0);
    if (eq == 0xFFFFFFFFFFFFFFFFull) {
        h.x += __shfl_xor(h.x, 16); h.y += __shfl_xor(h.y, 16);
        h.z += __shfl_xor(h.z, 16); h.w += __shfl_xor(h.w, 16);
        h.x += __shfl_xor(h.x, 32); h.y += __shfl_xor(h.y, 32);
        h.z += __shfl_xor(h.z, 32); h.w += __shfl_xor(h.w, 32);
        if (lane < 16) {
            float* hp = Hsum + (size_t)j * 64 + 4 * l;
            unsafeAtomicAdd(hp + 0, h.x);
            unsafeAtomicAdd(hp + 1, h.y);
            unsafeAtomicAdd(hp + 2, h.z);
            unsafeAtomicAdd(hp + 3, h.w);
        }
    } else {
        float* hp = Hsum + (size_t)j * 64 + 4 * l;
        unsafeAtomicAdd(hp + 0, h.x);
        unsafeAtomicAdd(hp + 1, h.y);
        unsafeAtomicAdd(hp + 2, h.z);
        unsafeAtomicAdd(hp + 3, h.w);
    }
}

// ---- out = Hsum @ W2 + counts * b2 ---------------------------------------
__global__ __launch_bounds__(256) void final_node(
    const float* __restrict__ Hsum, const int* __restrict__ counts,
    const short* __restrict__ Wt2t, const float* __restrict__ b2,
    float* __restrict__ out, int N)
{
    const int wave = threadIdx.x >> 6, lane = threadIdx.x & 63;
    const int g = lane >> 4, col = lane & 15;
    const int base = blockIdx.x * 256 + wave * 64;

    float b2c[4];
#pragma unroll
    for (int nt = 0; nt < 4; nt++) b2c[nt] = b2[col + 16 * nt];

    f32x4 acc[4][4];
#pragma unroll
    for (int mt = 0; mt < 4; mt++)
#pragma unroll
        for (int nt = 0; nt < 4; nt++)
            acc[mt][nt] = (f32x4){0.f, 0.f, 0.f, 0.f};

#pragma unroll
    for (int ks = 0; ks < 2; ks++) {
        const int kk = ks * 32 + g * 8;
        short8 af[4], bf[4];
#pragma unroll
        for (int mt = 0; mt < 4; mt++) {
            int row = base + mt * 16 + col;
            row = (row < N) ? row : (N - 1);
            const float* s = Hsum + (size_t)row * 64 + kk;
            af[mt] = pack8(*(const float4*)s, *(const float4*)(s + 4));
        }
#pragma unroll
        for (int nt = 0; nt < 4; nt++)
            bf[nt] = *(const short8*)(Wt2t + (size_t)(col + 16 * nt) * 64 + kk);
#pragma unroll
        for (int mt = 0; mt < 4; mt++)
#pragma unroll
            for (int nt = 0; nt < 4; nt++)
                acc[mt][nt] = __builtin_amdgcn_mfma_f32_16x16x32_bf16(
                    af[mt], bf[nt], acc[mt][nt], 0, 0, 0);
    }

#pragma unroll
    for (int mt = 0; mt < 4; mt++)
#pragma unroll
        for (int r = 0; r < 4; r++) {
            int node = base + mt * 16 + g * 4 + r;
            if (node < N) {
                float d = (float)counts[node];
#pragma unroll
                for (int nt = 0; nt < 4; nt++)
                    out[(size_t)node * 64 + col + 16 * nt] =
                        acc[mt][nt][r] + d * b2c[nt];
            }
        }
}

extern "C" void kernel_launch(void* const* d_in, const int* in_sizes, int n_in,
                              void* d_out, int out_size, void* d_ws, size_t ws_size,
                              hipStream_t stream)
{
    const float* x   = (const float*)d_in[0];
    const int*   ei  = (const int*)  d_in[1];
    const float* ea  = (const float*)d_in[2];
    const float* W1  = (const float*)d_in[3];
    const float* b1  = (const float*)d_in[4];
    const float* gam = (const float*)d_in[5];
    const float* bet = (const float*)d_in[6];
    const float* W2  = (const float*)d_in[7];
    const float* b2  = (const float*)d_in[8];
    float* out = (float*)d_out;

    const int E = in_sizes[1] / 2;
    const int N = in_sizes[0] / 64;

    // ---- workspace layout (bytes) ----
    char* ws = (char*)d_ws;
    size_t o = 0;
    short* Wab   = (short*)(ws + o); o += 128 * 64 * 2;       // 16384
    short* W1cT  = (short*)(ws + o); o += 64 * 32 * 2;        // 4096
    short* Wt2t  = (short*)(ws + o); o += 64 * 64 * 2;        // 8192
    o = (o + 255) & ~(size_t)255;
    short* xab   = (short*)(ws + o); o += (size_t)N * 128 * 2;
    o = (o + 255) & ~(size_t)255;
    short* eaw   = (short*)(ws + o); o += (size_t)E * 64 * 2;
    o = (o + 255) & ~(size_t)255;
    int* inv     = (int*)(ws + o); o += (size_t)E * 4;
    int* src_s   = (int*)(ws + o); o += (size_t)E * 4;
    int* dst_s   = (int*)(ws + o); o += (size_t)E * 4;
    int* counts  = (int*)(ws + o); o += (size_t)N * 4;
    int* offs    = (int*)(ws + o); o += (size_t)N * 4;
    int* cursor  = (int*)(ws + o); o += (size_t)N * 4;
    int* bsum    = (int*)(ws + o); o += 512 * 4;
    o = (o + 255) & ~(size_t)255;
    float* Hsum  = (float*)(ws + o); o += (size_t)N * 64 * 4;

    hipMemsetAsync(counts, 0, (size_t)N * 4, stream);
    hipMemsetAsync(cursor, 0, (size_t)N * 4, stream);
    hipMemsetAsync(Hsum, 0, (size_t)N * 64 * 4, stream);

    {
        int total = 128 * 64 + 64 * 32 + 64 * 64;
        hipLaunchKernelGGL(prep_weights3, dim3((total + 255) / 256), dim3(256),
                           0, stream, W1, W2, Wab, W1cT, Wt2t);
    }
    hipLaunchKernelGGL(precompute_xab, dim3((N + 255) / 256), dim3(256),
                       0, stream, x, Wab, xab, N);
    hipLaunchKernelGGL(hist_kernel, dim3((E + 255) / 256), dim3(256),
                       0, stream, ei, counts, E);
    const int nB = (N + 255) / 256;
    hipLaunchKernelGGL(scan1, dim3(nB), dim3(256), 0, stream,
                       counts, offs, bsum, N);
    hipLaunchKernelGGL(scan2, dim3(1), dim3(512), 0, stream, bsum, nB);
    hipLaunchKernelGGL(scan3, dim3(nB), dim3(256), 0, stream, offs, bsum, N);
    hipLaunchKernelGGL(permute_kernel, dim3((E + 255) / 256), dim3(256),
                       0, stream, ei, offs, cursor, inv, src_s, dst_s, E);
    hipLaunchKernelGGL(eaw_mfma, dim3((E + 255) / 256), dim3(256),
                       0, stream, ea, W1cT, b1, inv, eaw, E);
    hipLaunchKernelGGL(edge_ln, dim3((E + 15) / 16), dim3(256), 0, stream,
                       (const unsigned short*)xab, (const unsigned short*)eaw,
                       src_s, dst_s, gam, bet, Hsum, E);
    hipLaunchKernelGGL(final_node, dim3((N + 255) / 256), dim3(256),
                       0, stream, Hsum, counts, Wt2t, b2, out, N);
}